// Round 9
// baseline (1964.216 us; speedup 1.0000x reference)
//
#include <hip/hip_runtime.h>

// Problem dims
#define TT 512
#define DXX 128
#define HH 256
#define DZZ 64

typedef __attribute__((ext_vector_type(8))) short short8;
typedef __attribute__((ext_vector_type(4))) float f32x4;

#define DEV static __device__ __forceinline__
#define MFMA(a,b,c) __builtin_amdgcn_mfma_f32_16x16x32_bf16((a),(b),(c),0,0,0)

DEV unsigned short f2bf(float f){
  unsigned u = __builtin_bit_cast(unsigned, f);
  u += 0x7FFFu + ((u >> 16) & 1u);          // RNE
  return (unsigned short)(u >> 16);
}
DEV unsigned pack2(float lo, float hi){     // 2 f32 -> packed bf16x2
  return (unsigned)f2bf(lo) | ((unsigned)f2bf(hi) << 16);
}
DEV float bfLO(unsigned u){ return __builtin_bit_cast(float, u << 16); }
DEV float bfHI(unsigned u){ return __builtin_bit_cast(float, u & 0xffff0000u); }
DEV float ftanh(float x){
  float a = fabsf(x);
  float e = __expf(-2.f * a);
  float r = __builtin_amdgcn_rcpf(1.f + e);
  float t = (1.f - e) * r;
  return copysignf(t, x);
}
DEV float fsoftplus(float x){
  float e = __expf(fminf(x, 20.f));
  float s = __logf(1.f + e);
  return (x > 20.f) ? x : s;
}
// LDS-visibility barrier: lgkm drain + s_barrier, no vmcnt drain.
DEV void barrier_l(){
  asm volatile("s_waitcnt lgkmcnt(0)\n\ts_barrier" ::: "memory");
}

// Fragment conventions (verified rounds 1-8, mfma_f32_16x16x32_bf16), swapped:
//   D = A*B, A = weight tile (16 out-cols x K), B = state^T (K x 16 batch).
//   A-frag: lane l elem e: W[outcol = l&15][k = (l>>4)*8 + e]
//   B-frag: lane l elem e: h[batch = l&15][k = (l>>4)*8 + e]
//   C/D:    lane l reg r:  value(batch = l&15, outcol = tile + 4*(l>>4) + r)

// ---------------------------------------------------------------------------
// Phase A: xp = X @ Wih^T + bih + bhh (both dirs), bf16 lane-packed:
// xpF[d][s][bq][q4][l][16]
// ---------------------------------------------------------------------------
__global__ __launch_bounds__(256, 2) void phaseA(
    const float* __restrict__ X,
    const float* __restrict__ WihF, const float* __restrict__ bihF, const float* __restrict__ bhhF,
    const float* __restrict__ WihB, const float* __restrict__ bihB, const float* __restrict__ bhhB,
    unsigned short* __restrict__ xpF)
{
  const int bid = blockIdx.x;
  const int d = bid >> 9, s = bid & 511;
  const int ts = d ? (TT - 1 - s) : s;
  const float* W  = d ? WihB : WihF;
  const float* bi = d ? bihB : bihF;
  const float* bh = d ? bhhB : bhhF;

  const int tid = threadIdx.x, q = tid >> 6, l = tid & 63;
  const int l15 = l & 15, l4 = l >> 4;

  short8 wf[4][4];
  f32x4 bias[4];
  #pragma unroll
  for (int ni = 0; ni < 4; ++ni){
    int n = 64*q + 16*ni + l15;
    #pragma unroll
    for (int ks = 0; ks < 4; ++ks){
      const float* p = W + (size_t)n * DXX + ks*32 + l4*8;
      short8 v;
      #pragma unroll
      for (int i = 0; i < 8; ++i) v[i] = (short)f2bf(p[i]);
      wf[ni][ks] = v;
    }
    int n0 = 64*q + 16*ni + 4*l4;
    float4 b1 = *(const float4*)(bi + n0);
    float4 b2 = *(const float4*)(bh + n0);
    bias[ni][0]=b1.x+b2.x; bias[ni][1]=b1.y+b2.y; bias[ni][2]=b1.z+b2.z; bias[ni][3]=b1.w+b2.w;
  }

  #pragma unroll
  for (int bq = 0; bq < 4; ++bq){
    const float* xr = X + ((size_t)ts * 64 + 16*bq + l15) * DXX;
    short8 xf[4];
    #pragma unroll
    for (int ks = 0; ks < 4; ++ks){
      const float* p = xr + ks*32 + l4*8;
      short8 v;
      #pragma unroll
      for (int i = 0; i < 8; ++i) v[i] = (short)f2bf(p[i]);
      xf[ks] = v;
    }
    f32x4 acc[4];
    #pragma unroll
    for (int ni = 0; ni < 4; ++ni) acc[ni] = MFMA(wf[ni][0], xf[0], bias[ni]);
    #pragma unroll
    for (int ks = 1; ks < 4; ++ks)
      #pragma unroll
      for (int ni = 0; ni < 4; ++ni)
        acc[ni] = MFMA(wf[ni][ks], xf[ks], acc[ni]);

    unsigned wd[8];
    #pragma unroll
    for (int ni = 0; ni < 4; ++ni){
      wd[ni*2]   = pack2(acc[ni][0], acc[ni][1]);
      wd[ni*2+1] = pack2(acc[ni][2], acc[ni][3]);
    }
    unsigned short* dst = xpF + ((((size_t)d*TT + s)*4 + bq)*4 + q)*1024 + (size_t)l*16;
    uint4 o0 = {wd[0], wd[1], wd[2], wd[3]};
    uint4 o1 = {wd[4], wd[5], wd[6], wd[7]};
    ((uint4*)dst)[0] = o0;
    ((uint4*)dst)[1] = o1;
  }
}

// ---------------------------------------------------------------------------
// Phase B: two RNN scans, 8 blocks (dir,bq) x 128 thr = 2 FAT waves.
// Each wave owns 128 out-cols; Whh slice in 256 VGPRs; per-CU LDS reads
// halved vs 4-wave split; direct global stores at end of step; 1 raw barrier.
// ---------------------------------------------------------------------------
__global__ __launch_bounds__(128, 1) void phaseB(
    const float* __restrict__ WhhF, const float* __restrict__ WhhB,
    const unsigned short* __restrict__ xpF, unsigned short* __restrict__ hF)
{
  const int dir = blockIdx.x >> 2, bq = blockIdx.x & 3;
  const float* Whh = dir ? WhhB : WhhF;
  const int tid = threadIdx.x, qc = tid >> 6, l = tid & 63;
  const int l15 = l & 15, l4 = l >> 4;
  const int swz = (l15 & 7) << 3;
  const int rbase = l15 * 256;

  __shared__ __attribute__((aligned(16))) unsigned short hbuf[2][4096];

  short8 wf[8][8];                       // 128 out-cols x 256 K  (256 VGPR)
  #pragma unroll
  for (int ni = 0; ni < 8; ++ni){
    int n = 128*qc + 16*ni + l15;
    #pragma unroll
    for (int ks = 0; ks < 8; ++ks){
      const float* p = Whh + (size_t)n * HH + ks*32 + l4*8;
      short8 v;
      #pragma unroll
      for (int i = 0; i < 8; ++i) v[i] = (short)f2bf(p[i]);
      wf[ni][ks] = v;
    }
  }
  for (int i = tid; i < 2048; i += 128) ((unsigned*)hbuf[0])[i] = 0u;  // h_0 = 0

  const size_t strideS = 16384;   // ushorts per timestep
  const size_t base = (size_t)dir*TT*strideS + (size_t)bq*4096 + (size_t)l*16;
  const unsigned short* xpP = xpF + base;
  unsigned short* hD = hF + base;

  uint4 xA[4], xB[4];
  #pragma unroll
  for (int hi = 0; hi < 2; ++hi)
    #pragma unroll
    for (int pt = 0; pt < 2; ++pt){
      xA[hi*2+pt] = *(const uint4*)(xpP + (size_t)(2*qc+hi)*1024 + pt*8);
      xB[hi*2+pt] = *(const uint4*)(xpP + strideS + (size_t)(2*qc+hi)*1024 + pt*8);
    }
  barrier_l();

  auto bstep = [&](int s, uint4 (&X)[4]){
    // acc <- xp (consume BEFORE prefetch overwrites X)
    f32x4 acc[8];
    #pragma unroll
    for (int ni = 0; ni < 8; ++ni){
      int hi = ni >> 2, no = ni & 3;
      uint4 u = X[hi*2 + (no >> 1)];
      unsigned w0 = (no & 1) ? u.z : u.x;
      unsigned w1 = (no & 1) ? u.w : u.y;
      acc[ni][0] = bfLO(w0); acc[ni][1] = bfHI(w0);
      acc[ni][2] = bfLO(w1); acc[ni][3] = bfHI(w1);
    }
    // prefetch xp for s+2
    {
      int sn = (s + 2 < TT) ? s + 2 : TT - 1;
      #pragma unroll
      for (int hi = 0; hi < 2; ++hi)
        #pragma unroll
        for (int pt = 0; pt < 2; ++pt)
          X[hi*2+pt] = *(const uint4*)(xpP + (size_t)sn*strideS + (size_t)(2*qc+hi)*1024 + pt*8);
    }
    // Whh * h_{s-1}^T : 8 chains of depth 8, reads chunked 4+4
    const unsigned short* RD = hbuf[s & 1];
    unsigned short* WR = hbuf[(s & 1) ^ 1];
    #pragma unroll
    for (int ksc = 0; ksc < 8; ksc += 4){
      short8 b[4];
      #pragma unroll
      for (int k2 = 0; k2 < 4; ++k2)
        b[k2] = *(const short8*)(RD + ((rbase + (ksc+k2)*32 + l4*8) ^ swz));
      #pragma unroll
      for (int k2 = 0; k2 < 4; ++k2)
        #pragma unroll
        for (int ni = 0; ni < 8; ++ni)
          acc[ni] = MFMA(wf[ni][ksc+k2], b[k2], acc[ni]);
    }
    // tanh + pack -> recurrent LDS; collect for global store
    unsigned wd[16];
    #pragma unroll
    for (int ni = 0; ni < 8; ++ni){
      float t0 = ftanh(acc[ni][0]), t1 = ftanh(acc[ni][1]);
      float t2 = ftanh(acc[ni][2]), t3 = ftanh(acc[ni][3]);
      unsigned lo = pack2(t0, t1), hi2 = pack2(t2, t3);
      wd[ni*2] = lo; wd[ni*2+1] = hi2;
      int ea = rbase + ((128*qc + 16*ni + 4*l4) ^ swz);
      uint2 v; v.x = lo; v.y = hi2;
      *(uint2*)(WR + ea) = v;
    }
    // direct global stores (after all loads of this step)
    {
      size_t off = (size_t)(dir ? (TT - 1 - s) : s) * strideS;
      #pragma unroll
      for (int hi = 0; hi < 2; ++hi){
        unsigned short* dst = hD + off + (size_t)(2*qc+hi)*1024;
        uint4 o0 = {wd[hi*8+0], wd[hi*8+1], wd[hi*8+2], wd[hi*8+3]};
        uint4 o1 = {wd[hi*8+4], wd[hi*8+5], wd[hi*8+6], wd[hi*8+7]};
        *(uint4*)dst       = o0;
        *(uint4*)(dst + 8) = o1;
      }
    }
    barrier_l();
  };

  for (int s = 0; s < TT; s += 2){
    bstep(s,     xA);
    bstep(s + 1, xB);
  }
}

// ---------------------------------------------------------------------------
// Phase P (parallel over t): Mpre = bmu + (Wmu/3)·(hl+hr), Spre analog.
// MS[t][bq][q4][l][8] = {mu f32x4 | sig f32x4}.  (unchanged)
// ---------------------------------------------------------------------------
__global__ __launch_bounds__(256, 2) void phaseP(
    const float* __restrict__ Wmu, const float* __restrict__ bmu,
    const float* __restrict__ Wsig,const float* __restrict__ bsig,
    const unsigned short* __restrict__ hF, float* __restrict__ MS)
{
  const int bid = blockIdx.x;
  const int t = bid >> 2, bq = bid & 3;
  const int tid = threadIdx.x, q = tid >> 6, l = tid & 63;
  const int l15 = l & 15, l4 = l >> 4;
  const int swz = (l15 & 7) << 3;
  const int rbase = l15 * 256;

  __shared__ __attribute__((aligned(16))) unsigned short hbuf[4096];

  short8 wm[8], wsg[8];
  {
    int r = 16*q + l15;
    #pragma unroll
    for (int ks = 0; ks < 8; ++ks){
      const float* pm = Wmu  + (size_t)r * HH + ks*32 + l4*8;
      const float* ps = Wsig + (size_t)r * HH + ks*32 + l4*8;
      short8 vm, vs;
      #pragma unroll
      for (int i = 0; i < 8; ++i){
        vm[i] = (short)f2bf(pm[i] * (1.f/3.f));
        vs[i] = (short)f2bf(ps[i] * (1.f/3.f));
      }
      wm[ks] = vm; wsg[ks] = vs;
    }
  }
  f32x4 bm4, bs4;
  {
    float4 a = *(const float4*)(bmu  + 16*q + 4*l4);
    float4 b = *(const float4*)(bsig + 16*q + 4*l4);
    bm4[0]=a.x; bm4[1]=a.y; bm4[2]=a.z; bm4[3]=a.w;
    bs4[0]=b.x; bs4[1]=b.y; bs4[2]=b.z; bs4[3]=b.w;
  }

  const size_t strideS = 16384;
  const size_t laneOff = (size_t)bq*4096 + (size_t)q*1024 + (size_t)l*16;
  const unsigned short* hl = hF + (size_t)t*strideS + laneOff;
  const unsigned short* hr = hl + (size_t)TT*strideS;
  {
    uint4 a0 = ((const uint4*)hl)[0], a1 = ((const uint4*)hl)[1];
    uint4 b0 = ((const uint4*)hr)[0], b1 = ((const uint4*)hr)[1];
    unsigned HL[8] = {a0.x,a0.y,a0.z,a0.w,a1.x,a1.y,a1.z,a1.w};
    unsigned HR[8] = {b0.x,b0.y,b0.z,b0.w,b1.x,b1.y,b1.z,b1.w};
    #pragma unroll
    for (int ni = 0; ni < 4; ++ni){
      float h0 = bfLO(HL[ni*2])   + bfLO(HR[ni*2]);
      float h1 = bfHI(HL[ni*2])   + bfHI(HR[ni*2]);
      float h2 = bfLO(HL[ni*2+1]) + bfLO(HR[ni*2+1]);
      float h3 = bfHI(HL[ni*2+1]) + bfHI(HR[ni*2+1]);
      int ea = rbase + ((64*q + 16*ni + 4*l4) ^ swz);
      uint2 v; v.x = pack2(h0, h1); v.y = pack2(h2, h3);
      *(uint2*)(hbuf + ea) = v;
    }
  }
  __syncthreads();

  short8 hb[8];
  #pragma unroll
  for (int ks = 0; ks < 8; ++ks)
    hb[ks] = *(const short8*)(hbuf + ((rbase + ks*32 + l4*8) ^ swz));
  const f32x4 zero4 = {0.f,0.f,0.f,0.f};
  f32x4 am0 = MFMA(wm[0],  hb[0], bm4);
  f32x4 as0 = MFMA(wsg[0], hb[0], bs4);
  f32x4 am1 = MFMA(wm[4],  hb[4], zero4);
  f32x4 as1 = MFMA(wsg[4], hb[4], zero4);
  #pragma unroll
  for (int ks = 1; ks < 4; ++ks){
    am0 = MFMA(wm[ks],    hb[ks],   am0);
    as0 = MFMA(wsg[ks],   hb[ks],   as0);
    am1 = MFMA(wm[ks+4],  hb[ks+4], am1);
    as1 = MFMA(wsg[ks+4], hb[ks+4], as1);
  }
  f32x4 mu = am0 + am1;
  f32x4 sg = as0 + as1;
  float* dst = MS + ((((size_t)t*4 + bq)*4 + q)*64 + (size_t)l)*8;
  *(float4*)dst       = *(float4*)&mu;
  *(float4*)(dst + 4) = *(float4*)&sg;
}

// ---------------------------------------------------------------------------
// Phase C: latent scan, 4 blocks (bq) x 128 thr = 2 FAT waves, 2 raw barriers.
// Wave qc: transition u-cols [128qc,128qc+128), mu+sig cols [32qc,32qc+32).
// Prefetch t+2 ONLY AFTER MP/SP/EF are consumed (round-8 bug fixed).
// ---------------------------------------------------------------------------
__global__ __launch_bounds__(128, 1) void phaseC(
    const float* __restrict__ Wt,  const float* __restrict__ bt,
    const float* __restrict__ Wmu, const float* __restrict__ Wsig,
    const float* __restrict__ eps, const float* __restrict__ MS,
    float* __restrict__ out)
{
  const int bq = blockIdx.x;
  const int tid = threadIdx.x, qc = tid >> 6, l = tid & 63;
  const int l15 = l & 15, l4 = l >> 4;
  const int swz = (l15 & 7) << 3;
  const int rbase = l15 * 256;
  const int zrbase = l15 * 64;

  __shared__ __attribute__((aligned(16))) unsigned short zbuf[1024];   // 16 x 64 bf16
  __shared__ __attribute__((aligned(16))) unsigned short ubuf[4096];   // 16 x 256 bf16

  // transition: wave qc owns u-cols [128qc, 128qc+128), K = 64
  short8 wtf[8][2]; f32x4 btb[8];
  #pragma unroll
  for (int ni = 0; ni < 8; ++ni){
    int n = 128*qc + 16*ni + l15;
    #pragma unroll
    for (int ks = 0; ks < 2; ++ks){
      const float* p = Wt + (size_t)n * DZZ + ks*32 + l4*8;
      short8 v;
      #pragma unroll
      for (int i = 0; i < 8; ++i) v[i] = (short)f2bf(p[i]);
      wtf[ni][ks] = v;
    }
    float4 b4 = *(const float4*)(bt + 128*qc + 16*ni + 4*l4);
    btb[ni][0]=b4.x; btb[ni][1]=b4.y; btb[ni][2]=b4.z; btb[ni][3]=b4.w;
  }
  // mu/sig: wave qc owns out-cols [32qc, 32qc+32) of each, K = 256, /3 folded
  short8 wm[2][8], wsg[2][8];
  #pragma unroll
  for (int nj = 0; nj < 2; ++nj){
    int r = 32*qc + 16*nj + l15;
    #pragma unroll
    for (int ks = 0; ks < 8; ++ks){
      const float* pm = Wmu  + (size_t)r * HH + ks*32 + l4*8;
      const float* ps = Wsig + (size_t)r * HH + ks*32 + l4*8;
      short8 vm, vs;
      #pragma unroll
      for (int i = 0; i < 8; ++i){
        vm[i] = (short)f2bf(pm[i] * (1.f/3.f));
        vs[i] = (short)f2bf(ps[i] * (1.f/3.f));
      }
      wm[nj][ks] = vm; wsg[nj][ks] = vs;
    }
  }
  for (int i = tid; i < 512; i += 128) ((unsigned*)zbuf)[i] = 0u;   // z_0 = 0

  // MS: [t][bq][q4][l][8]; wave qc consumes q4 = 2qc+nj
  const float* msP = MS + (((size_t)bq*4 + 2*qc)*64 + (size_t)l)*8;   // + t*8192 + nj*512
  const float* eP  = eps + ((size_t)(16*bq + l15))*64 + 32*qc + 4*l4; // + t*4096 + nj*16
  const size_t TBZ = (size_t)TT * 64 * 64;

  f32x4 MPa[2], SPa[2], EFa[2], MPb[2], SPb[2], EFb[2];
  #pragma unroll
  for (int nj = 0; nj < 2; ++nj){
    float4 m0 = *(const float4*)(msP + nj*512);
    float4 s0 = *(const float4*)(msP + nj*512 + 4);
    float4 m1 = *(const float4*)(msP + 8192 + nj*512);
    float4 s1 = *(const float4*)(msP + 8192 + nj*512 + 4);
    float4 e0 = *(const float4*)(eP + nj*16);
    float4 e1 = *(const float4*)(eP + 4096 + nj*16);
    MPa[nj][0]=m0.x;MPa[nj][1]=m0.y;MPa[nj][2]=m0.z;MPa[nj][3]=m0.w;
    SPa[nj][0]=s0.x;SPa[nj][1]=s0.y;SPa[nj][2]=s0.z;SPa[nj][3]=s0.w;
    MPb[nj][0]=m1.x;MPb[nj][1]=m1.y;MPb[nj][2]=m1.z;MPb[nj][3]=m1.w;
    SPb[nj][0]=s1.x;SPb[nj][1]=s1.y;SPb[nj][2]=s1.z;SPb[nj][3]=s1.w;
    EFa[nj][0]=e0.x;EFa[nj][1]=e0.y;EFa[nj][2]=e0.z;EFa[nj][3]=e0.w;
    EFb[nj][0]=e1.x;EFb[nj][1]=e1.y;EFb[nj][2]=e1.z;EFb[nj][3]=e1.w;
  }
  barrier_l();

  auto cstep = [&](int t, f32x4 (&MP)[2], f32x4 (&SP)[2], f32x4 (&EF)[2]){
    // sect1: transition Wt*z^T + bt over this wave's 128 u-cols
    short8 zb0 = *(const short8*)(zbuf + ((zrbase +  0 + l4*8) ^ swz));
    short8 zb1 = *(const short8*)(zbuf + ((zrbase + 32 + l4*8) ^ swz));
    f32x4 at[8];
    #pragma unroll
    for (int ni = 0; ni < 8; ++ni) at[ni] = MFMA(wtf[ni][0], zb0, btb[ni]);
    #pragma unroll
    for (int ni = 0; ni < 8; ++ni) at[ni] = MFMA(wtf[ni][1], zb1, at[ni]);
    #pragma unroll
    for (int ni = 0; ni < 8; ++ni){
      float u0 = ftanh(at[ni][0]), u1 = ftanh(at[ni][1]);
      float u2 = ftanh(at[ni][2]), u3 = ftanh(at[ni][3]);
      int ea = rbase + ((128*qc + 16*ni + 4*l4) ^ swz);
      uint2 v; v.x = pack2(u0, u1); v.y = pack2(u2, u3);
      *(uint2*)(ubuf + ea) = v;
    }
    barrier_l();   // B1: ubuf (u_t) visible

    // sect2: mu/sig = Mpre/Spre + (W/3)·u ; reads chunked 4+4
    f32x4 am[2], as2[2];
    #pragma unroll
    for (int ksc = 0; ksc < 8; ksc += 4){
      short8 hb[4];
      #pragma unroll
      for (int k2 = 0; k2 < 4; ++k2)
        hb[k2] = *(const short8*)(ubuf + ((rbase + (ksc+k2)*32 + l4*8) ^ swz));
      if (ksc == 0){
        #pragma unroll
        for (int nj = 0; nj < 2; ++nj){ am[nj] = MP[nj]; as2[nj] = SP[nj]; }
      }
      #pragma unroll
      for (int k2 = 0; k2 < 4; ++k2)
        #pragma unroll
        for (int nj = 0; nj < 2; ++nj){
          am[nj]  = MFMA(wm[nj][ksc+k2],  hb[k2], am[nj]);
          as2[nj] = MFMA(wsg[nj][ksc+k2], hb[k2], as2[nj]);
        }
    }
    // reparam into locals (consumes EF) BEFORE the prefetch overwrites it
    f32x4 dz[2], dsp[2];
    #pragma unroll
    for (int nj = 0; nj < 2; ++nj)
      #pragma unroll
      for (int reg = 0; reg < 4; ++reg){
        float sp = fsoftplus(as2[nj][reg]);
        dz[nj][reg]  = __builtin_fmaf(sp, EF[nj][reg], am[nj][reg]);
        dsp[nj][reg] = sp;
      }
    // prefetch t+2 (MS + eps) — MP/SP/EF all consumed above
    {
      int tn = (t + 2 < TT) ? t + 2 : TT - 1;
      #pragma unroll
      for (int nj = 0; nj < 2; ++nj){
        float4 m = *(const float4*)(msP + (size_t)tn*8192 + nj*512);
        float4 s = *(const float4*)(msP + (size_t)tn*8192 + nj*512 + 4);
        float4 e = *(const float4*)(eP + (size_t)tn*4096 + nj*16);
        MP[nj][0]=m.x;MP[nj][1]=m.y;MP[nj][2]=m.z;MP[nj][3]=m.w;
        SP[nj][0]=s.x;SP[nj][1]=s.y;SP[nj][2]=s.z;SP[nj][3]=s.w;
        EF[nj][0]=e.x;EF[nj][1]=e.y;EF[nj][2]=e.z;EF[nj][3]=e.w;
      }
    }
    // z -> zbuf; direct global stores (after all loads)
    #pragma unroll
    for (int nj = 0; nj < 2; ++nj){
      int zea = zrbase + ((32*qc + 16*nj + 4*l4) ^ swz);
      uint2 v; v.x = pack2(dz[nj][0], dz[nj][1]); v.y = pack2(dz[nj][2], dz[nj][3]);
      *(uint2*)(zbuf + zea) = v;
      size_t ob = ((size_t)t*64 + 16*bq + l15)*64 + 32*qc + 16*nj + 4*l4;
      *(float4*)(out + ob)         = *(float4*)&dz[nj];
      *(float4*)(out + TBZ + ob)   = *(float4*)&am[nj];
      *(float4*)(out + 2*TBZ + ob) = *(float4*)&dsp[nj];
    }
    barrier_l();   // B2: z_t visible
  };

  for (int t = 0; t < TT; t += 2){
    cstep(t,     MPa, SPa, EFa);
    cstep(t + 1, MPb, SPb, EFb);
  }
}

// ---------------------------------------------------------------------------
extern "C" void kernel_launch(void* const* d_in, const int* in_sizes, int n_in,
                              void* d_out, int out_size, void* d_ws, size_t ws_size,
                              hipStream_t stream)
{
  const float* X      = (const float*)d_in[0];
  const float* Wih_f  = (const float*)d_in[1];
  const float* Whh_f  = (const float*)d_in[2];
  const float* bih_f  = (const float*)d_in[3];
  const float* bhh_f  = (const float*)d_in[4];
  const float* Wih_b  = (const float*)d_in[5];
  const float* Whh_b  = (const float*)d_in[6];
  const float* bih_b  = (const float*)d_in[7];
  const float* bhh_b  = (const float*)d_in[8];
  const float* Wt     = (const float*)d_in[9];
  const float* bt     = (const float*)d_in[10];
  const float* Wmu    = (const float*)d_in[11];
  const float* bmu    = (const float*)d_in[12];
  const float* Wsig   = (const float*)d_in[13];
  const float* bsig   = (const float*)d_in[14];
  const float* eps    = (const float*)d_in[15];

  // Workspace: xpF (33.5MB) + hF (33.5MB); MS (16.8MB) aliases xpF
  // (phaseP runs after phaseB, the last reader of xpF).
  unsigned short* xpF = (unsigned short*)d_ws;
  unsigned short* hF  = xpF + (size_t)2 * TT * 16384;
  float* MS = (float*)d_ws;

  phaseA<<<dim3(1024), dim3(256), 0, stream>>>(X, Wih_f, bih_f, bhh_f, Wih_b, bih_b, bhh_b, xpF);
  phaseB<<<dim3(8), dim3(128), 0, stream>>>(Whh_f, Whh_b, xpF, hF);
  phaseP<<<dim3(2048), dim3(256), 0, stream>>>(Wmu, bmu, Wsig, bsig, hF, MS);
  phaseC<<<dim3(4), dim3(128), 0, stream>>>(Wt, bt, Wmu, Wsig, eps, MS, (float*)d_out);
}

// Round 10
// 1684.252 us; speedup vs baseline: 1.1662x; 1.1662x over previous
//
#include <hip/hip_runtime.h>
#include <hip/hip_bf16.h>

// Problem dims
#define TT 512
#define DXX 128
#define HH 256
#define DZZ 64

typedef __attribute__((ext_vector_type(8))) short short8;
typedef __attribute__((ext_vector_type(4))) float f32x4;

#define DEV static __device__ __forceinline__
#define MFMA(a,b,c) __builtin_amdgcn_mfma_f32_16x16x32_bf16((a),(b),(c),0,0,0)

DEV unsigned short f2bf(float f){            // init-path only
  unsigned u = __builtin_bit_cast(unsigned, f);
  u += 0x7FFFu + ((u >> 16) & 1u);
  return (unsigned short)(u >> 16);
}
DEV unsigned pack2(float lo, float hi){      // hot path: v_cvt_pk_bf16_f32
  __hip_bfloat162 v = __float22bfloat162_rn(float2{lo, hi});
  unsigned r; __builtin_memcpy(&r, &v, 4);
  return r;
}
DEV float bfLO(unsigned u){ return __builtin_bit_cast(float, u << 16); }
DEV float bfHI(unsigned u){ return __builtin_bit_cast(float, u & 0xffff0000u); }
DEV float ftanh(float x){                    // 1 - 2/(1+2^(2x*log2e)); inf-safe both ends
  float e = exp2f(x * 2.885390082f);
  float r = __builtin_amdgcn_rcpf(1.f + e);
  return __builtin_fmaf(-2.f, r, 1.f);
}
DEV float fsoftplus(float x){
  float e = __expf(fminf(x, 20.f));
  float s = __logf(1.f + e);
  return (x > 20.f) ? x : s;
}
// LDS-visibility barrier: lgkm drain + s_barrier, no vmcnt drain.
DEV void barrier_l(){
  asm volatile("s_waitcnt lgkmcnt(0)\n\ts_barrier" ::: "memory");
}

// Fragment conventions (verified rounds 1-9, mfma_f32_16x16x32_bf16), swapped:
//   D = A*B, A = weight tile (16 out-cols x K), B = state^T (K x 16 batch).
//   A-frag: lane l elem e: W[outcol = l&15][k = (l>>4)*8 + e]
//   B-frag: lane l elem e: h[batch = l&15][k = (l>>4)*8 + e]
//   C/D:    lane l reg r:  value(batch = l&15, outcol = tile + 4*(l>>4) + r)

// ---------------------------------------------------------------------------
// Phase A: xp = X @ Wih^T + bih + bhh (both dirs), bf16 lane-packed:
// xpF[d][s][bq][q4][l][16]
// ---------------------------------------------------------------------------
__global__ __launch_bounds__(256, 2) void phaseA(
    const float* __restrict__ X,
    const float* __restrict__ WihF, const float* __restrict__ bihF, const float* __restrict__ bhhF,
    const float* __restrict__ WihB, const float* __restrict__ bihB, const float* __restrict__ bhhB,
    unsigned short* __restrict__ xpF)
{
  const int bid = blockIdx.x;
  const int d = bid >> 9, s = bid & 511;
  const int ts = d ? (TT - 1 - s) : s;
  const float* W  = d ? WihB : WihF;
  const float* bi = d ? bihB : bihF;
  const float* bh = d ? bhhB : bhhF;

  const int tid = threadIdx.x, q = tid >> 6, l = tid & 63;
  const int l15 = l & 15, l4 = l >> 4;

  short8 wf[4][4];
  f32x4 bias[4];
  #pragma unroll
  for (int ni = 0; ni < 4; ++ni){
    int n = 64*q + 16*ni + l15;
    #pragma unroll
    for (int ks = 0; ks < 4; ++ks){
      const float* p = W + (size_t)n * DXX + ks*32 + l4*8;
      short8 v;
      #pragma unroll
      for (int i = 0; i < 8; ++i) v[i] = (short)f2bf(p[i]);
      wf[ni][ks] = v;
    }
    int n0 = 64*q + 16*ni + 4*l4;
    float4 b1 = *(const float4*)(bi + n0);
    float4 b2 = *(const float4*)(bh + n0);
    bias[ni][0]=b1.x+b2.x; bias[ni][1]=b1.y+b2.y; bias[ni][2]=b1.z+b2.z; bias[ni][3]=b1.w+b2.w;
  }

  #pragma unroll
  for (int bq = 0; bq < 4; ++bq){
    const float* xr = X + ((size_t)ts * 64 + 16*bq + l15) * DXX;
    short8 xf[4];
    #pragma unroll
    for (int ks = 0; ks < 4; ++ks){
      const float* p = xr + ks*32 + l4*8;
      short8 v;
      #pragma unroll
      for (int i = 0; i < 8; ++i) v[i] = (short)f2bf(p[i]);
      xf[ks] = v;
    }
    f32x4 acc[4];
    #pragma unroll
    for (int ni = 0; ni < 4; ++ni) acc[ni] = MFMA(wf[ni][0], xf[0], bias[ni]);
    #pragma unroll
    for (int ks = 1; ks < 4; ++ks)
      #pragma unroll
      for (int ni = 0; ni < 4; ++ni)
        acc[ni] = MFMA(wf[ni][ks], xf[ks], acc[ni]);

    unsigned wd[8];
    #pragma unroll
    for (int ni = 0; ni < 4; ++ni){
      wd[ni*2]   = pack2(acc[ni][0], acc[ni][1]);
      wd[ni*2+1] = pack2(acc[ni][2], acc[ni][3]);
    }
    unsigned short* dst = xpF + ((((size_t)d*TT + s)*4 + bq)*4 + q)*1024 + (size_t)l*16;
    uint4 o0 = {wd[0], wd[1], wd[2], wd[3]};
    uint4 o1 = {wd[4], wd[5], wd[6], wd[7]};
    ((uint4*)dst)[0] = o0;
    ((uint4*)dst)[1] = o1;
  }
}

// ---------------------------------------------------------------------------
// Phase B: BOTH RNN scans in each block. 4 blocks (bq) x 512 thr = 8 waves:
// waves 0-3 forward scan, waves 4-7 backward scan (independent LDS dbufs,
// shared barrier). 2 waves/SIMD -> mutual latency hiding.
// ---------------------------------------------------------------------------
__global__ __launch_bounds__(512, 1) void phaseB(
    const float* __restrict__ WhhF, const float* __restrict__ WhhB,
    const unsigned short* __restrict__ xpF, unsigned short* __restrict__ hF)
{
  const int bq = blockIdx.x;
  const int tid = threadIdx.x, w = tid >> 6, l = tid & 63;
  const int dir = w >> 2, qw = w & 3;
  const float* Whh = dir ? WhhB : WhhF;
  const int l15 = l & 15, l4 = l >> 4;
  const int swz = (l15 & 7) << 3;
  const int rbase = l15 * 256;

  __shared__ __attribute__((aligned(16))) unsigned short hbuf[2][2][4096]; // [dir][buf]

  short8 wf[4][8];
  #pragma unroll
  for (int ni = 0; ni < 4; ++ni){
    int n = 64*qw + 16*ni + l15;
    #pragma unroll
    for (int ks = 0; ks < 8; ++ks){
      const float* p = Whh + (size_t)n * HH + ks*32 + l4*8;
      short8 v;
      #pragma unroll
      for (int i = 0; i < 8; ++i) v[i] = (short)f2bf(p[i]);
      wf[ni][ks] = v;
    }
  }
  for (int i = tid; i < 2048; i += 512){          // h_0 = 0 for both dirs
    ((unsigned*)hbuf[0][0])[i] = 0u;
    ((unsigned*)hbuf[1][0])[i] = 0u;
  }

  const size_t strideS = 16384;   // ushorts per timestep
  const size_t laneOff = (size_t)bq*4096 + (size_t)qw*1024 + (size_t)l*16;
  const unsigned short* xpP = xpF + (size_t)dir*TT*strideS + laneOff;
  unsigned short* hD = hF + (size_t)dir*TT*strideS + laneOff;

  uint4 xqA0, xqA1, xqB0, xqB1;
  { const uint4* p = (const uint4*)xpP;             xqA0 = p[0]; xqA1 = p[1]; }
  { const uint4* p = (const uint4*)(xpP + strideS); xqB0 = p[0]; xqB1 = p[1]; }

  barrier_l();

  auto bstep = [&](int s, uint4& XQ0, uint4& XQ1){
    // 1) LDS reads of h_{s-1}
    const unsigned short* RD = hbuf[dir][s & 1];
    unsigned short* WR = hbuf[dir][(s & 1) ^ 1];
    short8 b[8];
    #pragma unroll
    for (int ks = 0; ks < 8; ++ks)
      b[ks] = *(const short8*)(RD + ((rbase + ks*32 + l4*8) ^ swz));
    // 2) acc <- xp (consume BEFORE prefetch overwrites)
    f32x4 accE[4], accO[4];
    {
      unsigned W8[8] = {XQ0.x, XQ0.y, XQ0.z, XQ0.w, XQ1.x, XQ1.y, XQ1.z, XQ1.w};
      #pragma unroll
      for (int ni = 0; ni < 4; ++ni){
        accE[ni][0] = bfLO(W8[ni*2]);   accE[ni][1] = bfHI(W8[ni*2]);
        accE[ni][2] = bfLO(W8[ni*2+1]); accE[ni][3] = bfHI(W8[ni*2+1]);
        accO[ni][0] = 0.f; accO[ni][1] = 0.f; accO[ni][2] = 0.f; accO[ni][3] = 0.f;
      }
    }
    // 3) prefetch xp for s+2
    {
      int sn = (s + 2 < TT) ? s + 2 : TT - 1;
      const uint4* src = (const uint4*)(xpP + (size_t)sn * strideS);
      XQ0 = src[0]; XQ1 = src[1];
    }
    // 4) Whh * h^T : 8 chains of depth 4
    #pragma unroll
    for (int ks = 0; ks < 8; ks += 2){
      #pragma unroll
      for (int ni = 0; ni < 4; ++ni){
        accE[ni] = MFMA(wf[ni][ks],   b[ks],   accE[ni]);
        accO[ni] = MFMA(wf[ni][ks+1], b[ks+1], accO[ni]);
      }
    }
    // 5) tanh + pack -> LDS; 6) direct global store (after the loads)
    unsigned wd[8];
    #pragma unroll
    for (int ni = 0; ni < 4; ++ni){
      float t0 = ftanh(accE[ni][0] + accO[ni][0]);
      float t1 = ftanh(accE[ni][1] + accO[ni][1]);
      float t2 = ftanh(accE[ni][2] + accO[ni][2]);
      float t3 = ftanh(accE[ni][3] + accO[ni][3]);
      unsigned lo = pack2(t0, t1), hi = pack2(t2, t3);
      wd[ni*2] = lo; wd[ni*2+1] = hi;
      int ea = rbase + ((64*qw + 16*ni + 4*l4) ^ swz);
      uint2 v; v.x = lo; v.y = hi;
      *(uint2*)(WR + ea) = v;
    }
    {
      size_t off = (size_t)(dir ? (TT - 1 - s) : s) * strideS;
      uint4 o0 = {wd[0], wd[1], wd[2], wd[3]};
      uint4 o1 = {wd[4], wd[5], wd[6], wd[7]};
      *(uint4*)(hD + off)     = o0;
      *(uint4*)(hD + off + 8) = o1;
    }
    barrier_l();
  };

  for (int s = 0; s < TT; s += 2){
    bstep(s,     xqA0, xqA1);
    bstep(s + 1, xqB0, xqB1);
  }
}

// ---------------------------------------------------------------------------
// Phase P (parallel over t): Mpre = bmu + (Wmu/3)·(hl+hr), Spre analog.
// MS[t][bq][q4][l][8] = {mu f32x4 | sig f32x4}.
// ---------------------------------------------------------------------------
__global__ __launch_bounds__(256, 2) void phaseP(
    const float* __restrict__ Wmu, const float* __restrict__ bmu,
    const float* __restrict__ Wsig,const float* __restrict__ bsig,
    const unsigned short* __restrict__ hF, float* __restrict__ MS)
{
  const int bid = blockIdx.x;
  const int t = bid >> 2, bq = bid & 3;
  const int tid = threadIdx.x, q = tid >> 6, l = tid & 63;
  const int l15 = l & 15, l4 = l >> 4;
  const int swz = (l15 & 7) << 3;
  const int rbase = l15 * 256;

  __shared__ __attribute__((aligned(16))) unsigned short hbuf[4096];

  short8 wm[8], wsg[8];
  {
    int r = 16*q + l15;
    #pragma unroll
    for (int ks = 0; ks < 8; ++ks){
      const float* pm = Wmu  + (size_t)r * HH + ks*32 + l4*8;
      const float* ps = Wsig + (size_t)r * HH + ks*32 + l4*8;
      short8 vm, vs;
      #pragma unroll
      for (int i = 0; i < 8; ++i){
        vm[i] = (short)f2bf(pm[i] * (1.f/3.f));
        vs[i] = (short)f2bf(ps[i] * (1.f/3.f));
      }
      wm[ks] = vm; wsg[ks] = vs;
    }
  }
  f32x4 bm4, bs4;
  {
    float4 a = *(const float4*)(bmu  + 16*q + 4*l4);
    float4 b = *(const float4*)(bsig + 16*q + 4*l4);
    bm4[0]=a.x; bm4[1]=a.y; bm4[2]=a.z; bm4[3]=a.w;
    bs4[0]=b.x; bs4[1]=b.y; bs4[2]=b.z; bs4[3]=b.w;
  }

  const size_t strideS = 16384;
  const size_t laneOff = (size_t)bq*4096 + (size_t)q*1024 + (size_t)l*16;
  const unsigned short* hl = hF + (size_t)t*strideS + laneOff;
  const unsigned short* hr = hl + (size_t)TT*strideS;
  {
    uint4 a0 = ((const uint4*)hl)[0], a1 = ((const uint4*)hl)[1];
    uint4 b0 = ((const uint4*)hr)[0], b1 = ((const uint4*)hr)[1];
    unsigned HL[8] = {a0.x,a0.y,a0.z,a0.w,a1.x,a1.y,a1.z,a1.w};
    unsigned HR[8] = {b0.x,b0.y,b0.z,b0.w,b1.x,b1.y,b1.z,b1.w};
    #pragma unroll
    for (int ni = 0; ni < 4; ++ni){
      float h0 = bfLO(HL[ni*2])   + bfLO(HR[ni*2]);
      float h1 = bfHI(HL[ni*2])   + bfHI(HR[ni*2]);
      float h2 = bfLO(HL[ni*2+1]) + bfLO(HR[ni*2+1]);
      float h3 = bfHI(HL[ni*2+1]) + bfHI(HR[ni*2+1]);
      int ea = rbase + ((64*q + 16*ni + 4*l4) ^ swz);
      uint2 v; v.x = pack2(h0, h1); v.y = pack2(h2, h3);
      *(uint2*)(hbuf + ea) = v;
    }
  }
  __syncthreads();

  short8 hb[8];
  #pragma unroll
  for (int ks = 0; ks < 8; ++ks)
    hb[ks] = *(const short8*)(hbuf + ((rbase + ks*32 + l4*8) ^ swz));
  const f32x4 zero4 = {0.f,0.f,0.f,0.f};
  f32x4 am0 = MFMA(wm[0],  hb[0], bm4);
  f32x4 as0 = MFMA(wsg[0], hb[0], bs4);
  f32x4 am1 = MFMA(wm[4],  hb[4], zero4);
  f32x4 as1 = MFMA(wsg[4], hb[4], zero4);
  #pragma unroll
  for (int ks = 1; ks < 4; ++ks){
    am0 = MFMA(wm[ks],    hb[ks],   am0);
    as0 = MFMA(wsg[ks],   hb[ks],   as0);
    am1 = MFMA(wm[ks+4],  hb[ks+4], am1);
    as1 = MFMA(wsg[ks+4], hb[ks+4], as1);
  }
  f32x4 mu = am0 + am1;
  f32x4 sg = as0 + as1;
  float* dst = MS + ((((size_t)t*4 + bq)*4 + q)*64 + (size_t)l)*8;
  *(float4*)dst       = *(float4*)&mu;
  *(float4*)(dst + 4) = *(float4*)&sg;
}

// ---------------------------------------------------------------------------
// Phase C: latent scan, 2 blocks x 512 thr = 8 waves: waves 0-3 handle
// bq = 2*blk, waves 4-7 handle bq = 2*blk+1 (independent LDS, shared
// barriers). r7 Mpre/Spre hoist; r9 consume-then-prefetch; direct stores.
// ---------------------------------------------------------------------------
__global__ __launch_bounds__(512, 1) void phaseC(
    const float* __restrict__ Wt,  const float* __restrict__ bt,
    const float* __restrict__ Wmu, const float* __restrict__ Wsig,
    const float* __restrict__ eps, const float* __restrict__ MS,
    float* __restrict__ out)
{
  const int tid = threadIdx.x, w = tid >> 6, l = tid & 63;
  const int g = w >> 2, qw = w & 3;
  const int bq = 2*blockIdx.x + g;
  const int l15 = l & 15, l4 = l >> 4;
  const int swz = (l15 & 7) << 3;
  const int rbase = l15 * 256;
  const int zrbase = l15 * 64;

  __shared__ __attribute__((aligned(16))) unsigned short zbuf[2][1024];  // [g]
  __shared__ __attribute__((aligned(16))) unsigned short ubuf[2][4096];  // [g]

  // transition: wave qw owns u-cols [64qw, 64qw+64), K = 64
  short8 wtf[4][2]; f32x4 btb[4];
  #pragma unroll
  for (int ni = 0; ni < 4; ++ni){
    int n = 64*qw + 16*ni + l15;
    #pragma unroll
    for (int ks = 0; ks < 2; ++ks){
      const float* p = Wt + (size_t)n * DZZ + ks*32 + l4*8;
      short8 v;
      #pragma unroll
      for (int i = 0; i < 8; ++i) v[i] = (short)f2bf(p[i]);
      wtf[ni][ks] = v;
    }
    float4 b4 = *(const float4*)(bt + 64*qw + 16*ni + 4*l4);
    btb[ni][0]=b4.x; btb[ni][1]=b4.y; btb[ni][2]=b4.z; btb[ni][3]=b4.w;
  }
  // mu/sig: wave qw owns out-cols [16qw,16qw+16) of each, K = 256, /3 folded
  short8 wm[8], wsg[8];
  {
    int r = 16*qw + l15;
    #pragma unroll
    for (int ks = 0; ks < 8; ++ks){
      const float* pm = Wmu  + (size_t)r * HH + ks*32 + l4*8;
      const float* ps = Wsig + (size_t)r * HH + ks*32 + l4*8;
      short8 vm, vs;
      #pragma unroll
      for (int i = 0; i < 8; ++i){
        vm[i] = (short)f2bf(pm[i] * (1.f/3.f));
        vs[i] = (short)f2bf(ps[i] * (1.f/3.f));
      }
      wm[ks] = vm; wsg[ks] = vs;
    }
  }
  for (int i = tid; i < 1024; i += 512) ((unsigned*)zbuf)[i] = 0u;   // z_0 = 0 (both g)

  const size_t strideS = 16384;
  const float* msP = MS + (((size_t)bq*4 + qw)*64 + (size_t)l)*8;       // + t*8192
  const float* eP  = eps + ((size_t)(16*bq + l15))*64 + 16*qw + 4*l4;   // + t*4096
  const size_t TBZ = (size_t)TT * 64 * 64;
  const f32x4 zero4 = {0.f,0.f,0.f,0.f};

  f32x4 MPa, SPa, EFa, MPb, SPb, EFb;
  {
    float4 m0 = *(const float4*)(msP);         float4 s0 = *(const float4*)(msP + 4);
    float4 m1 = *(const float4*)(msP + 8192);  float4 s1 = *(const float4*)(msP + 8192 + 4);
    float4 e0 = *(const float4*)(eP);
    float4 e1 = *(const float4*)(eP + 4096);
    MPa[0]=m0.x;MPa[1]=m0.y;MPa[2]=m0.z;MPa[3]=m0.w;
    SPa[0]=s0.x;SPa[1]=s0.y;SPa[2]=s0.z;SPa[3]=s0.w;
    MPb[0]=m1.x;MPb[1]=m1.y;MPb[2]=m1.z;MPb[3]=m1.w;
    SPb[0]=s1.x;SPb[1]=s1.y;SPb[2]=s1.z;SPb[3]=s1.w;
    EFa[0]=e0.x;EFa[1]=e0.y;EFa[2]=e0.z;EFa[3]=e0.w;
    EFb[0]=e1.x;EFb[1]=e1.y;EFb[2]=e1.z;EFb[3]=e1.w;
  }
  barrier_l();

  auto cstep = [&](int t, f32x4& MP, f32x4& SP, f32x4& EF){
    // sect1: transition Wt*z^T + bt -> tanh -> ubuf[g]
    short8 zb0 = *(const short8*)(zbuf[g] + ((zrbase +  0 + l4*8) ^ swz));
    short8 zb1 = *(const short8*)(zbuf[g] + ((zrbase + 32 + l4*8) ^ swz));
    f32x4 at[4];
    #pragma unroll
    for (int ni = 0; ni < 4; ++ni) at[ni] = MFMA(wtf[ni][0], zb0, btb[ni]);
    #pragma unroll
    for (int ni = 0; ni < 4; ++ni) at[ni] = MFMA(wtf[ni][1], zb1, at[ni]);
    #pragma unroll
    for (int ni = 0; ni < 4; ++ni){
      float u0 = ftanh(at[ni][0]), u1 = ftanh(at[ni][1]);
      float u2 = ftanh(at[ni][2]), u3 = ftanh(at[ni][3]);
      int ea = rbase + ((64*qw + 16*ni + 4*l4) ^ swz);
      uint2 v; v.x = pack2(u0, u1); v.y = pack2(u2, u3);
      *(uint2*)(ubuf[g] + ea) = v;
    }
    barrier_l();   // B1: u_t visible

    // sect2: mu/sig = Mpre/Spre + (W/3)·u
    short8 hb[8];
    #pragma unroll
    for (int ks = 0; ks < 8; ++ks)
      hb[ks] = *(const short8*)(ubuf[g] + ((rbase + ks*32 + l4*8) ^ swz));
    f32x4 am0 = MFMA(wm[0],  hb[0], MP);
    f32x4 as0 = MFMA(wsg[0], hb[0], SP);
    f32x4 am1 = MFMA(wm[4],  hb[4], zero4);
    f32x4 as1 = MFMA(wsg[4], hb[4], zero4);
    #pragma unroll
    for (int ks = 1; ks < 4; ++ks){
      am0 = MFMA(wm[ks],    hb[ks],   am0);
      as0 = MFMA(wsg[ks],   hb[ks],   as0);
      am1 = MFMA(wm[ks+4],  hb[ks+4], am1);
      as1 = MFMA(wsg[ks+4], hb[ks+4], as1);
    }
    f32x4 mu = am0 + am1;
    f32x4 sg = as0 + as1;
    // reparam (consumes EF) BEFORE prefetch overwrites it
    f32x4 dz, dsp;
    #pragma unroll
    for (int reg = 0; reg < 4; ++reg){
      float sp = fsoftplus(sg[reg]);
      dz[reg]  = __builtin_fmaf(sp, EF[reg], mu[reg]);
      dsp[reg] = sp;
    }
    // prefetch t+2 (MP/SP/EF consumed above)
    {
      int tn = (t + 2 < TT) ? t + 2 : TT - 1;
      float4 m = *(const float4*)(msP + (size_t)tn*8192);
      float4 s = *(const float4*)(msP + (size_t)tn*8192 + 4);
      float4 e = *(const float4*)(eP + (size_t)tn*4096);
      MP[0]=m.x;MP[1]=m.y;MP[2]=m.z;MP[3]=m.w;
      SP[0]=s.x;SP[1]=s.y;SP[2]=s.z;SP[3]=s.w;
      EF[0]=e.x;EF[1]=e.y;EF[2]=e.z;EF[3]=e.w;
    }
    // z -> zbuf[g]; direct global stores (after all loads)
    {
      int zea = zrbase + ((16*qw + 4*l4) ^ swz);
      uint2 v; v.x = pack2(dz[0], dz[1]); v.y = pack2(dz[2], dz[3]);
      *(uint2*)(zbuf[g] + zea) = v;
      size_t ob = ((size_t)t*64 + 16*bq + l15)*64 + 16*qw + 4*l4;
      *(float4*)(out + ob)         = *(float4*)&dz;
      *(float4*)(out + TBZ + ob)   = *(float4*)&mu;
      *(float4*)(out + 2*TBZ + ob) = *(float4*)&dsp;
    }
    barrier_l();   // B2: z_t visible
  };

  for (int t = 0; t < TT; t += 2){
    cstep(t,     MPa, SPa, EFa);
    cstep(t + 1, MPb, SPb, EFb);
  }
}

// ---------------------------------------------------------------------------
extern "C" void kernel_launch(void* const* d_in, const int* in_sizes, int n_in,
                              void* d_out, int out_size, void* d_ws, size_t ws_size,
                              hipStream_t stream)
{
  const float* X      = (const float*)d_in[0];
  const float* Wih_f  = (const float*)d_in[1];
  const float* Whh_f  = (const float*)d_in[2];
  const float* bih_f  = (const float*)d_in[3];
  const float* bhh_f  = (const float*)d_in[4];
  const float* Wih_b  = (const float*)d_in[5];
  const float* Whh_b  = (const float*)d_in[6];
  const float* bih_b  = (const float*)d_in[7];
  const float* bhh_b  = (const float*)d_in[8];
  const float* Wt     = (const float*)d_in[9];
  const float* bt     = (const float*)d_in[10];
  const float* Wmu    = (const float*)d_in[11];
  const float* bmu    = (const float*)d_in[12];
  const float* Wsig   = (const float*)d_in[13];
  const float* bsig   = (const float*)d_in[14];
  const float* eps    = (const float*)d_in[15];

  // Workspace: xpF (33.5MB) + hF (33.5MB); MS (16.8MB) aliases xpF
  // (phaseP runs after phaseB, the last reader of xpF).
  unsigned short* xpF = (unsigned short*)d_ws;
  unsigned short* hF  = xpF + (size_t)2 * TT * 16384;
  float* MS = (float*)d_ws;

  phaseA<<<dim3(1024), dim3(256), 0, stream>>>(X, Wih_f, bih_f, bhh_f, Wih_b, bih_b, bhh_b, xpF);
  phaseB<<<dim3(4), dim3(512), 0, stream>>>(Whh_f, Whh_b, xpF, hF);
  phaseP<<<dim3(2048), dim3(256), 0, stream>>>(Wmu, bmu, Wsig, bsig, hF, MS);
  phaseC<<<dim3(2), dim3(512), 0, stream>>>(Wt, bt, Wmu, Wsig, eps, MS, (float*)d_out);
}